// Round 15
// baseline (229.727 us; speedup 1.0000x reference)
//
#include <hip/hip_runtime.h>
#include <hip/hip_bf16.h>

#define B_   2
#define SQ_  2048
#define DM_  1024
#define NH_  16
#define DH_  64

typedef __attribute__((ext_vector_type(8))) short          bf16x8;
typedef __attribute__((ext_vector_type(4))) short          bf16x4;
typedef __attribute__((ext_vector_type(8))) unsigned short u16x8;
typedef __attribute__((ext_vector_type(4))) float          f32x4;

__device__ __forceinline__ unsigned short f2bf(float f) {
    union { __hip_bfloat16 h; unsigned short u; } c;
    c.h = __float2bfloat16(f);   // RNE
    return c.u;
}
__device__ __forceinline__ float gsum16(float v) {
    v += __shfl_xor(v, 1);
    v += __shfl_xor(v, 2);
    v += __shfl_xor(v, 4);
    v += __shfl_xor(v, 8);
    return v;
}

// 16x16x16 bf16 MFMA (A/B = 4 bf16 = 2 VGPR). Builtin name differs across
// ROCm versions; fall back to inline asm (instruction exists on gfx950).
__device__ __forceinline__ f32x4 mfma16(bf16x4 a, bf16x4 b, f32x4 c) {
#if __has_builtin(__builtin_amdgcn_mfma_f32_16x16x16bf16_1k)
    return __builtin_amdgcn_mfma_f32_16x16x16bf16_1k(a, b, c, 0, 0, 0);
#else
    asm("v_mfma_f32_16x16x16_bf16 %0, %1, %2, %0" : "+v"(c) : "v"(a), "v"(b));
    return c;
#endif
}

// async global->LDS, 16B per lane. LDS dest is linear: wave base + lane*16.
__device__ __forceinline__ void gll16(const unsigned short* g, unsigned short* l) {
    __builtin_amdgcn_global_load_lds(
        (const __attribute__((address_space(1))) unsigned int*)g,
        (__attribute__((address_space(3))) unsigned int*)l,
        16, 0, 0);
}

// One launch: 4 weight transposes (bf16) + x_q/x_kv f32->bf16 conversion.
// bid<768: W_Q/W_K/W_V (16 mats of 1024x64 each, 256 blocks per tensor).
// 768..1023: W_O (1024x1024). 1024..2047: convert x_q (512) / x_kv (512),
// 8 rows/block for TLP on the latency-bound conversion.
__global__ __launch_bounds__(256) void prep_all(
    const float* __restrict__ W_Q, const float* __restrict__ W_K,
    const float* __restrict__ W_V, const float* __restrict__ W_O,
    const float* __restrict__ x_q, const float* __restrict__ x_kv,
    unsigned short* __restrict__ WTq, unsigned short* __restrict__ WTkv,
    unsigned short* __restrict__ WTo,
    unsigned short* __restrict__ xqbf, unsigned short* __restrict__ xkvbf)
{
    const int bid = blockIdx.x, tid = threadIdx.x;
    if (bid >= 1024) {   // elementwise f32 -> bf16 (8192-float chunks)
        const int cid = bid - 1024;
        const float* src = (cid < 512) ? x_q : x_kv;
        unsigned short* dst = (cid < 512) ? xqbf : xkvbf;
        const size_t base = (size_t)(cid & 511) * 8192 + tid * 4;
#pragma unroll
        for (int i = 0; i < 8; ++i) {
            const float4 v = *(const float4*)(src + base + i * 1024);
            ushort4 o;
            o.x = f2bf(v.x); o.y = f2bf(v.y); o.z = f2bf(v.z); o.w = f2bf(v.w);
            *(ushort4*)(dst + base + i * 1024) = o;
        }
        return;
    }
    __shared__ float t[64][65];
    const float* src; unsigned short* dst; int R, C, r0, c0;
    if (bid < 768) {
        const int which = bid >> 8, rem = bid & 255;
        const int rblk = rem & 15, zz = rem >> 4;
        src = (which == 0) ? W_Q : (which == 1) ? W_K : W_V;
        dst = (which == 0) ? WTq : (which == 1) ? WTkv : (WTkv + (1u << 20));
        src += (size_t)65536 * zz;
        dst += (size_t)65536 * zz;
        R = 1024; C = 64; r0 = rblk * 64; c0 = 0;
    } else {
        const int rem = bid - 768;
        src = W_O; dst = WTo; R = 1024; C = 1024;
        r0 = (rem & 15) * 64; c0 = (rem >> 4) * 64;
    }
    const int lr = tid >> 6, lc = tid & 63;
#pragma unroll
    for (int i = 0; i < 16; ++i)
        t[lr + i * 4][lc] = src[(size_t)(r0 + lr + i * 4) * C + c0 + lc];
    __syncthreads();
    // vectorized transposed write: thread (u = tid&15, w0 = tid>>4) writes
    // ushort4 at dst[(c0+c)*R + r0 + 4u]  (8B stores, 128B/row segments)
    const int u = tid & 15, w0 = tid >> 4;
#pragma unroll
    for (int i = 0; i < 4; ++i) {
        const int cl = w0 + i * 16;
        ushort4 o;
        o.x = f2bf(t[4 * u + 0][cl]);
        o.y = f2bf(t[4 * u + 1][cl]);
        o.z = f2bf(t[4 * u + 2][cl]);
        o.w = f2bf(t[4 * u + 3][cl]);
        *(ushort4*)&dst[(size_t)(c0 + cl) * R + r0 + 4 * u] = o;
    }
}

// C[4096 x N] = A[4096 x 1024] * W(+bias).  A bf16 [m][k]; WT bf16 [c][k].
// TM x 128 tile, BK=64, NT threads (NT/64 waves as (NW/2)x2; wave tile
// (2*TM/NW) x 64). global_load_lds staging into LDS [rows][64] with XOR
// slot-swizzle (source pre-swizzle + same involution on ds_read; 0 bank
// conflicts). Controlling metric: STAGING BYTES PER MFMA (round 13: TM=32's
// 640 B/MFMA regressed despite 47% occupancy; TM=64 = 384; TM=128 = 256).
// Explicit dbuf (round 4) and XCD-chunk swizzle (round 7) measured slower.
// MODE 0: Q  -> per-head LN, bf16 out (Cb)
// MODE 1: KV -> N=2048; c<1024: K (LN, f32 Cf + bf16 Cb); c>=1024: V
//               (f32 Cf2 row-major + bf16 CbT transposed [b][h][d][s])
// MODE 2: O  -> f32 out (Cf)
template <int TM, int MODE, int NT>
__device__ __forceinline__ void gemm_body(
    unsigned short (*__restrict__ As)[64], unsigned short (*__restrict__ Bs)[64],
    int bx, int by, const unsigned short* __restrict__ Abf,
    const unsigned short* __restrict__ WT,
    const float* __restrict__ biasK, const float* __restrict__ biasV,
    const float* __restrict__ lnw, const float* __restrict__ lnb,
    float* __restrict__ Cf, float* __restrict__ Cf2,
    unsigned short* __restrict__ Cb, unsigned short* __restrict__ CbT, int tid)
{
    constexpr int NW    = NT / 64;            // waves per block
    constexpr int WROWS = 2 * TM / NW;        // wave row-tile
    constexpr int MI    = WROWS / 16;         // acc row-fragments per wave
    constexpr int RP    = NT / 8;             // rows staged per gll16 pass
    constexpr int APASS = TM / RP;            // A staging passes (>=1)
    constexpr int BPASS = 128 / RP;           // B staging passes

    const int m0 = by * TM;
    const int c0 = bx * 128;

    const int wid = tid >> 6, lane = tid & 63;
    const int wm = (wid >> 1) * WROWS;
    const int wn = (wid & 1) * 64;
    const int l15 = lane & 15, qd = lane >> 4;

    // staging: thread t -> physical LDS (row = t>>3 (+RP*j), slot = t&7).
    // Source col is pre-swizzled: s = p ^ (row&7). (RP multiple of 8.)
    const int srow  = tid >> 3;
    const int pslot = tid & 7;
    const int sslot = pslot ^ (srow & 7);
    const unsigned short* Ag = Abf + (size_t)(m0 + srow) * 1024 + sslot * 8;
    const unsigned short* Bg = WT  + (size_t)(c0 + srow) * 1024 + sslot * 8;
    unsigned short* Al = &As[srow][pslot * 8];
    unsigned short* Bl = &Bs[srow][pslot * 8];

    const f32x4 zero4 = {0.f, 0.f, 0.f, 0.f};
    f32x4 acc[MI][4];
#pragma unroll
    for (int mi = 0; mi < MI; ++mi)
#pragma unroll
        for (int ni = 0; ni < 4; ++ni) acc[mi][ni] = zero4;

    const int r7 = l15 & 7;   // row&7 of every fragment row this lane reads

    for (int kb = 0; kb < 16; ++kb) {
        const size_t kof = (size_t)kb * 64;
        __syncthreads();                       // prior tile's LDS reads done
#pragma unroll
        for (int j = 0; j < APASS; ++j)
            gll16(Ag + (size_t)j * RP * 1024 + kof, Al + j * RP * 64);
#pragma unroll
        for (int j = 0; j < BPASS; ++j)
            gll16(Bg + (size_t)j * RP * 1024 + kof, Bl + j * RP * 64);
        __syncthreads();                       // drains vmcnt -> LDS ready
#pragma unroll
        for (int ks = 0; ks < 2; ++ks) {
            const int cs = ((ks * 4 + qd) ^ r7) * 8;   // swizzled col (shorts)
            bf16x8 af[MI], bfr[4];
#pragma unroll
            for (int mi = 0; mi < MI; ++mi)
                af[mi] = *(const bf16x8*)&As[wm + mi * 16 + l15][cs];
#pragma unroll
            for (int ni = 0; ni < 4; ++ni)
                bfr[ni] = *(const bf16x8*)&Bs[wn + ni * 16 + l15][cs];
#pragma unroll
            for (int mi = 0; mi < MI; ++mi)
#pragma unroll
                for (int ni = 0; ni < 4; ++ni)
                    acc[mi][ni] = __builtin_amdgcn_mfma_f32_16x16x32_bf16(
                        af[mi], bfr[ni], acc[mi][ni], 0, 0, 0);
        }
    }

    const float* bias = (MODE == 1 && c0 >= 1024) ? biasV : biasK;
    float bv[4];
#pragma unroll
    for (int ni = 0; ni < 4; ++ni) bv[ni] = bias[(c0 + wn + ni * 16 + l15) & 1023];
#pragma unroll
    for (int mi = 0; mi < MI; ++mi)
#pragma unroll
        for (int ni = 0; ni < 4; ++ni)
#pragma unroll
            for (int r = 0; r < 4; ++r) acc[mi][ni][r] += bv[ni];

    if constexpr (MODE != 2) {
        const bool doLN = (MODE == 0) || (c0 < 1024);
        if (doLN) {   // per-head LN: wave's 64 cols = exactly one head
            float w4[4], lb4[4];
#pragma unroll
            for (int ni = 0; ni < 4; ++ni) {
                w4[ni]  = lnw[ni * 16 + l15];
                lb4[ni] = lnb[ni * 16 + l15];
            }
#pragma unroll
            for (int mi = 0; mi < MI; ++mi)
#pragma unroll
                for (int r = 0; r < 4; ++r) {
                    float s1 = acc[mi][0][r] + acc[mi][1][r] + acc[mi][2][r] + acc[mi][3][r];
                    const float mu = gsum16(s1) * (1.0f / 64.0f);
                    float s2 = acc[mi][0][r] * acc[mi][0][r] + acc[mi][1][r] * acc[mi][1][r]
                             + acc[mi][2][r] * acc[mi][2][r] + acc[mi][3][r] * acc[mi][3][r];
                    const float var = gsum16(s2) * (1.0f / 64.0f) - mu * mu;
                    const float rstd = rsqrtf(var + 1e-5f);
#pragma unroll
                    for (int ni = 0; ni < 4; ++ni)
                        acc[mi][ni][r] = (acc[mi][ni][r] - mu) * rstd * w4[ni] + lb4[ni];
                }
        }
    }

    if constexpr (MODE == 0) {
#pragma unroll
        for (int mi = 0; mi < MI; ++mi)
#pragma unroll
            for (int r = 0; r < 4; ++r) {
                const size_t grow = m0 + wm + mi * 16 + qd * 4 + r;
#pragma unroll
                for (int ni = 0; ni < 4; ++ni)
                    Cb[grow * 1024 + c0 + wn + ni * 16 + l15] = f2bf(acc[mi][ni][r]);
            }
    } else if constexpr (MODE == 2) {
#pragma unroll
        for (int mi = 0; mi < MI; ++mi)
#pragma unroll
            for (int r = 0; r < 4; ++r) {
                const size_t grow = m0 + wm + mi * 16 + qd * 4 + r;
#pragma unroll
                for (int ni = 0; ni < 4; ++ni)
                    Cf[grow * 1024 + c0 + wn + ni * 16 + l15] = acc[mi][ni][r];
            }
    } else {
        if (c0 < 1024) {   // K half
#pragma unroll
            for (int mi = 0; mi < MI; ++mi)
#pragma unroll
                for (int r = 0; r < 4; ++r) {
                    const size_t grow = m0 + wm + mi * 16 + qd * 4 + r;
#pragma unroll
                    for (int ni = 0; ni < 4; ++ni) {
                        const int gcol = c0 + wn + ni * 16 + l15;
                        Cf[grow * 1024 + gcol] = acc[mi][ni][r];
                        Cb[grow * 1024 + gcol] = f2bf(acc[mi][ni][r]);
                    }
                }
        } else {           // V half: row-major f32 + transposed bf16
#pragma unroll
            for (int mi = 0; mi < MI; ++mi) {
                const int growb = m0 + wm + mi * 16 + qd * 4;
                const int bb_ = growb >> 11, ss = growb & 2047;
#pragma unroll
                for (int ni = 0; ni < 4; ++ni) {
                    const int gv = c0 - 1024 + wn + ni * 16 + l15;
                    const int hh = gv >> 6, dd = gv & 63;
#pragma unroll
                    for (int r = 0; r < 4; ++r)
                        Cf2[(size_t)(growb + r) * 1024 + gv] = acc[mi][ni][r];
                    ushort4 w;
                    w.x = f2bf(acc[mi][ni][0]); w.y = f2bf(acc[mi][ni][1]);
                    w.z = f2bf(acc[mi][ni][2]); w.w = f2bf(acc[mi][ni][3]);
                    *(ushort4*)&CbT[(((size_t)bb_ * NH_ + hh) * DH_ + dd) * SQ_ + ss] = w;
                }
            }
        }
    }
}

// KV gemm (512 blocks) + Q gemm (256 blocks) in one 768-block launch.
// NT=512, TM=128: 32KB LDS, 8 waves/block -> 3 blocks/CU = 24 waves/CU at
// the best staging ratio (256 B/MFMA). Round-14 verified config.
__global__ __launch_bounds__(512) void qkv_fused(
    const unsigned short* __restrict__ xqbf, const unsigned short* __restrict__ xkvbf,
    const unsigned short* __restrict__ WTq, const unsigned short* __restrict__ WTkv,
    const float* __restrict__ b_Q, const float* __restrict__ b_K,
    const float* __restrict__ b_V,
    const float* __restrict__ ln1w, const float* __restrict__ ln1b,
    const float* __restrict__ ln2w, const float* __restrict__ ln2b,
    float* __restrict__ kout, float* __restrict__ vout,
    unsigned short* __restrict__ qz, unsigned short* __restrict__ kbf,
    unsigned short* __restrict__ vbfT)
{
    __shared__ __align__(16) unsigned short As[128][64];
    __shared__ __align__(16) unsigned short Bs[128][64];
    const int bid = blockIdx.x, tid = threadIdx.x;
    if (bid < 512) {
        gemm_body<128, 1, 512>(As, Bs, bid & 15, bid >> 4, xkvbf, WTkv, b_K, b_V,
                               ln2w, ln2b, kout, vout, kbf, vbfT, tid);
    } else {
        const int b2 = bid - 512;
        gemm_body<128, 0, 512>(As, Bs, b2 & 7, b2 >> 3, xqbf, WTq, b_Q, nullptr,
                               ln1w, ln1b, nullptr, nullptr, qz, nullptr, tid);
    }
}

// TM=64/NT=512: 384 B/MFMA (round 13: TM=32's 640 was the bad ratio) and
// 512 blocks x 8 waves = 2 blocks/CU = 16 waves/CU (was 8 at TM=32/NT=256).
__global__ __launch_bounds__(512) void o_gemm(
    const unsigned short* __restrict__ zbf, const unsigned short* __restrict__ WTo,
    const float* __restrict__ b_O, float* __restrict__ out)
{
    __shared__ __align__(16) unsigned short As[64][64];
    __shared__ __align__(16) unsigned short Bs[128][64];
    gemm_body<64, 2, 512>(As, Bs, blockIdx.x, blockIdx.y, zbf, WTo, b_O, nullptr,
                          nullptr, nullptr, out, nullptr, nullptr, nullptr,
                          threadIdx.x);
}

// causal flash attention, S^T formulation; 64 q-rows/block; PAIRED hi-lo
// q-tiles (uniform 34 kv-tiles/block -- robust to undefined dispatch order,
// which broke the unpaired variants in rounds 1/8).
// 8-WAVE KV-PARITY SPLIT: block = 512 threads. Wave (g = wid&3, p = wid>>2):
// group g owns q-rows g*16+l15; parity p owns kv-tiles == p (mod 2).
// STATIC-MAX softmax (no running max) makes kv-splitting embarrassingly
// parallel: partials combine as z = z0+z1, l = l0+l1 via one LDS exchange
// per pass. 2 blocks x 8 waves = 16 waves/CU.
// SUPER-TILE DOUBLE BUFFER (round 15): one barrier per super-step (the
// round-2 single-barrier pattern applied to the 8-wave kernel): prefetch
// regs at top, compute buf[cur], late-write buf[cur^1], single barrier.
// LDS 73.7KB still allows the wave-capped 2 blocks/CU.
// REGISTER PV (round 11): pa=bf16(s) feeds v_mfma 16x16x16 directly; V read
// from VsT as bf16x4 (2-way bank aliasing = free). Epilogue combine reuses
// staging LDS as scratch after a barrier.
__global__ __launch_bounds__(512) void attn_mfma(
    unsigned short* __restrict__ qz, const unsigned short* __restrict__ kbf,
    const unsigned short* __restrict__ vbfT)
{
    __shared__ __align__(16) unsigned short Ks[2][128][72];    // [buf][kv][d]
    __shared__ __align__(16) unsigned short VsT[2][64][136];   // [buf][d][kv]

    const int tid = threadIdx.x;
    const int h = blockIdx.y, b = blockIdx.z;
    const int wid = tid >> 6, lane = tid & 63;
    const int g = wid & 3, p = wid >> 2;      // q-group, kv-parity
    const int l15 = lane & 15, qd = lane >> 4;
    const int srow = tid >> 2, scol = (tid & 3) * 16;   // K staging (128 rows)
    const int vrow = tid >> 3, vcol = (tid & 7) * 16;   // V staging (64 rows)

    const size_t kbase = (size_t)b * SQ_ * DM_ + (size_t)h * DH_;
    const size_t vbase = ((size_t)b * NH_ + h) * DH_ * (size_t)SQ_;
    const f32x4 zero4 = {0.f, 0.f, 0.f, 0.f};
    const float LOG2E = 1.44269504f, MBIAS = 46.1662413f;   // 32*log2(e)

    float* zs = (float*)&Ks[0][0][0];    // epilogue scratch (aliases Ks[0], 16KB)
    float* ls = (float*)&VsT[0][0][0];   // epilogue scratch (aliases VsT[0], 1KB)

    for (int pass = 0; pass < 2; ++pass) {
        const int qt = pass ? blockIdx.x : 31 - blockIdx.x;   // bx 0..15

        // Q fragments (B-operand: n=l15 -> qrow, k=qd*8+j -> d), direct global
        bf16x8 qf[2];
        {
            const unsigned short* qp =
                qz + kbase + (size_t)(qt * 64 + g * 16 + l15) * DM_ + qd * 8;
            qf[0] = *(const bf16x8*)(qp);
            qf[1] = *(const bf16x8*)(qp + 32);
        }

        f32x4 z[4];
#pragma unroll
        for (int ni = 0; ni < 4; ++ni) z[ni] = zero4;
        float l_i = 0.f;

        {   // stage super-tile 0 into buf0 (prior pass's last barrier protects)
            const unsigned short* ks = kbf + kbase + (size_t)srow * DM_ + scol;
            const u16x8 a0 = *(const u16x8*)(ks);
            const u16x8 a1 = *(const u16x8*)(ks + 8);
            const unsigned short* vs = vbfT + vbase + (size_t)vrow * SQ_ + vcol;
            const u16x8 b0 = *(const u16x8*)(vs);
            const u16x8 b1 = *(const u16x8*)(vs + 8);
            *(u16x8*)&Ks[0][srow][scol + 0]  = a0;
            *(u16x8*)&Ks[0][srow][scol + 8]  = a1;
            *(u16x8*)&VsT[0][vrow][vcol + 0] = b0;
            *(u16x8*)&VsT[0][vrow][vcol + 8] = b1;
        }
        __syncthreads();

        const int NS = (qt >> 1) + 1;   // super-steps (2 kv-tiles each)
        for (int st = 0; st < NS; ++st) {
            const int cur = st & 1;

            // issue next super-tile's global loads (overlap with compute)
            u16x8 kr0, kr1, vr0, vr1;
            if (st < NS - 1) {
                const unsigned short* ks =
                    kbf + kbase + (size_t)((st + 1) * 128 + srow) * DM_ + scol;
                kr0 = *(const u16x8*)(ks);
                kr1 = *(const u16x8*)(ks + 8);
                const unsigned short* vs =
                    vbfT + vbase + (size_t)vrow * SQ_ + (st + 1) * 128 + vcol;
                vr0 = *(const u16x8*)(vs);
                vr1 = *(const u16x8*)(vs + 8);
            }

            const int kt = st * 2 + p;   // this wave's kv-tile
            if (kt <= qt) {
                // S^T = K Q^T : lane holds S^T[kv=mi*16+qd*4+r][q=l15]
                f32x4 s[4];
#pragma unroll
                for (int mi = 0; mi < 4; ++mi) s[mi] = zero4;
#pragma unroll
                for (int ks2 = 0; ks2 < 2; ++ks2)
#pragma unroll
                    for (int mi = 0; mi < 4; ++mi) {
                        const bf16x8 af = *(const bf16x8*)
                            &Ks[cur][p * 64 + mi * 16 + l15][ks2 * 32 + qd * 8];
                        s[mi] = __builtin_amdgcn_mfma_f32_16x16x32_bf16(
                            af, qf[ks2], s[mi], 0, 0, 0);
                    }

                if (kt == qt) {   // causal mask (tile-local): kv > q
#pragma unroll
                    for (int mi = 0; mi < 4; ++mi)
#pragma unroll
                        for (int r = 0; r < 4; ++r)
                            if (mi * 16 + qd * 4 + r > g * 16 + l15)
                                s[mi][r] = -3.0e38f;
                }

                // static-max softmax: p' = exp2(s*log2e - 32*log2e)
                float ts[4];
                bf16x4 pa[4];
#pragma unroll
                for (int mi = 0; mi < 4; ++mi) {
#pragma unroll
                    for (int r = 0; r < 4; ++r)
                        s[mi][r] = __builtin_amdgcn_exp2f(
                            fmaf(s[mi][r], LOG2E, -MBIAS));
                    ts[mi] = (s[mi][0] + s[mi][1]) + (s[mi][2] + s[mi][3]);
                    pa[mi][0] = (short)f2bf(s[mi][0]);
                    pa[mi][1] = (short)f2bf(s[mi][1]);
                    pa[mi][2] = (short)f2bf(s[mi][2]);
                    pa[mi][3] = (short)f2bf(s[mi][3]);
                }
                float rs = (ts[0] + ts[1]) + (ts[2] + ts[3]);
                rs += __shfl_xor(rs, 16);
                rs += __shfl_xor(rs, 32);
                l_i += rs;

                // z += P V, P direct from registers (16x16x16)
#pragma unroll
                for (int mi = 0; mi < 4; ++mi)
#pragma unroll
                    for (int ni = 0; ni < 4; ++ni) {
                        const bf16x4 bv = *(const bf16x4*)
                            &VsT[cur][ni * 16 + l15][p * 64 + mi * 16 + qd * 4];
                        z[ni] = mfma16(pa[mi], bv, z[ni]);
                    }
            }

            // late write of the prefetched super-tile into the other buffer;
            // its last readers finished before the PREVIOUS barrier
            if (st < NS - 1) {
                *(u16x8*)&Ks[cur ^ 1][srow][scol + 0]  = kr0;
                *(u16x8*)&Ks[cur ^ 1][srow][scol + 8]  = kr1;
                *(u16x8*)&VsT[cur ^ 1][vrow][vcol + 0] = vr0;
                *(u16x8*)&VsT[cur ^ 1][vrow][vcol + 8] = vr1;
            }
            __syncthreads();   // single barrier per super-step
        }

        // combine kv-parity partials: z = z0 + z1, l = l0 + l1
        if (p == 1) {
#pragma unroll
            for (int ni = 0; ni < 4; ++ni)
                *(f32x4*)&zs[((g * 4 + ni) * 64 + lane) * 4] = z[ni];
            ls[g * 64 + lane] = l_i;
        }
        __syncthreads();
        if (p == 0) {
            const float l_tot = l_i + ls[g * 64 + lane];
#pragma unroll
            for (int ni = 0; ni < 4; ++ni) {
                const f32x4 zo = *(const f32x4*)&zs[((g * 4 + ni) * 64 + lane) * 4];
#pragma unroll
                for (int r = 0; r < 4; ++r) z[ni][r] += zo[r];
            }
            const float linv = 1.0f / l_tot;
#pragma unroll
            for (int r = 0; r < 4; ++r) {
                const float lr_ = __shfl(linv, qd * 4 + r);
                const size_t row = (size_t)qt * 64 + g * 16 + qd * 4 + r;
#pragma unroll
                for (int ni = 0; ni < 4; ++ni)
                    qz[kbase + row * DM_ + ni * 16 + l15] = f2bf(z[ni][r] * lr_);
            }
        }
        __syncthreads();   // scratch reads done before next pass restages
    }
}

extern "C" void kernel_launch(void* const* d_in, const int* in_sizes, int n_in,
                              void* d_out, int out_size, void* d_ws, size_t ws_size,
                              hipStream_t stream)
{
    const float* x_q  = (const float*)d_in[0];
    const float* x_kv = (const float*)d_in[1];
    // d_in[2] = mask (causal tril) -- computed analytically
    const float* W_Q  = (const float*)d_in[3];
    const float* W_K  = (const float*)d_in[4];
    const float* W_V  = (const float*)d_in[5];
    const float* W_O  = (const float*)d_in[6];
    const float* b_Q  = (const float*)d_in[7];
    const float* b_K  = (const float*)d_in[8];
    const float* b_V  = (const float*)d_in[9];
    const float* b_O  = (const float*)d_in[10];
    const float* ln1w = (const float*)d_in[11];
    const float* ln1b = (const float*)d_in[12];
    const float* ln2w = (const float*)d_in[13];
    const float* ln2b = (const float*)d_in[14];

    const size_t NTOK = (size_t)B_ * SQ_;          // 4096
    float* out  = (float*)d_out;
    float* kout = out + NTOK * DM_;
    float* vout = kout + NTOK * DM_;

    // bf16 copies of x_q/x_kv live in the `out` region (16 MB) of d_out:
    // written by prep_all, read by qkv_fused, overwritten by o_gemm last.
    unsigned short* xqbf  = (unsigned short*)out;
    unsigned short* xkvbf = xqbf + (1u << 22);

    unsigned short* wsu  = (unsigned short*)d_ws;
    unsigned short* WTq  = wsu;                        // 1M elems
    unsigned short* WTkv = WTq + (1u << 20);           // 2M (K^T | V^T)
    unsigned short* WTo  = WTkv + (2u << 20);          // 1M
    unsigned short* qz   = WTo + (1u << 20);           // 4M
    unsigned short* kbf  = qz + (1u << 22);            // 4M
    unsigned short* vbfT = kbf + (1u << 22);           // 4M -> 32 MiB total

    prep_all<<<2048, 256, 0, stream>>>(W_Q, W_K, W_V, W_O, x_q, x_kv,
                                       WTq, WTkv, WTo, xqbf, xkvbf);

    qkv_fused<<<768, 512, 0, stream>>>(xqbf, xkvbf, WTq, WTkv, b_Q, b_K, b_V,
                                       ln1w, ln1b, ln2w, ln2b,
                                       kout, vout, qz, kbf, vbfT);

    attn_mfma<<<dim3(16, NH_, B_), 512, 0, stream>>>(qz, kbf, vbfT);

    o_gemm<<<dim3(8, 64), 512, 0, stream>>>(qz, WTo, b_O, out);
}

// Round 16
// 225.892 us; speedup vs baseline: 1.0170x; 1.0170x over previous
//
#include <hip/hip_runtime.h>
#include <hip/hip_bf16.h>

#define B_   2
#define SQ_  2048
#define DM_  1024
#define NH_  16
#define DH_  64

typedef __attribute__((ext_vector_type(8))) short          bf16x8;
typedef __attribute__((ext_vector_type(4))) short          bf16x4;
typedef __attribute__((ext_vector_type(8))) unsigned short u16x8;
typedef __attribute__((ext_vector_type(4))) float          f32x4;

__device__ __forceinline__ unsigned short f2bf(float f) {
    union { __hip_bfloat16 h; unsigned short u; } c;
    c.h = __float2bfloat16(f);   // RNE
    return c.u;
}
__device__ __forceinline__ float gsum16(float v) {
    v += __shfl_xor(v, 1);
    v += __shfl_xor(v, 2);
    v += __shfl_xor(v, 4);
    v += __shfl_xor(v, 8);
    return v;
}

// 16x16x16 bf16 MFMA (A/B = 4 bf16 = 2 VGPR). Builtin name differs across
// ROCm versions; fall back to inline asm (instruction exists on gfx950).
__device__ __forceinline__ f32x4 mfma16(bf16x4 a, bf16x4 b, f32x4 c) {
#if __has_builtin(__builtin_amdgcn_mfma_f32_16x16x16bf16_1k)
    return __builtin_amdgcn_mfma_f32_16x16x16bf16_1k(a, b, c, 0, 0, 0);
#else
    asm("v_mfma_f32_16x16x16_bf16 %0, %1, %2, %0" : "+v"(c) : "v"(a), "v"(b));
    return c;
#endif
}

// counted vmcnt wait (immediate must be literal in the asm string)
template <int N> __device__ __forceinline__ void waitv() {
    if constexpr (N == 0)      asm volatile("s_waitcnt vmcnt(0)" ::: "memory");
    else if constexpr (N == 2) asm volatile("s_waitcnt vmcnt(2)" ::: "memory");
    else if constexpr (N == 3) asm volatile("s_waitcnt vmcnt(3)" ::: "memory");
    else if constexpr (N == 4) asm volatile("s_waitcnt vmcnt(4)" ::: "memory");
    else if constexpr (N == 6) asm volatile("s_waitcnt vmcnt(6)" ::: "memory");
}

// async global->LDS, 16B per lane. LDS dest is linear: wave base + lane*16.
__device__ __forceinline__ void gll16(const unsigned short* g, unsigned short* l) {
    __builtin_amdgcn_global_load_lds(
        (const __attribute__((address_space(1))) unsigned int*)g,
        (__attribute__((address_space(3))) unsigned int*)l,
        16, 0, 0);
}

// One launch: 4 weight transposes (bf16) + x_q/x_kv f32->bf16 conversion.
// bid<768: W_Q/W_K/W_V (16 mats of 1024x64 each, 256 blocks per tensor).
// 768..1023: W_O (1024x1024). 1024..2047: convert x_q (512) / x_kv (512),
// 8 rows/block for TLP on the latency-bound conversion.
__global__ __launch_bounds__(256) void prep_all(
    const float* __restrict__ W_Q, const float* __restrict__ W_K,
    const float* __restrict__ W_V, const float* __restrict__ W_O,
    const float* __restrict__ x_q, const float* __restrict__ x_kv,
    unsigned short* __restrict__ WTq, unsigned short* __restrict__ WTkv,
    unsigned short* __restrict__ WTo,
    unsigned short* __restrict__ xqbf, unsigned short* __restrict__ xkvbf)
{
    const int bid = blockIdx.x, tid = threadIdx.x;
    if (bid >= 1024) {   // elementwise f32 -> bf16 (8192-float chunks)
        const int cid = bid - 1024;
        const float* src = (cid < 512) ? x_q : x_kv;
        unsigned short* dst = (cid < 512) ? xqbf : xkvbf;
        const size_t base = (size_t)(cid & 511) * 8192 + tid * 4;
#pragma unroll
        for (int i = 0; i < 8; ++i) {
            const float4 v = *(const float4*)(src + base + i * 1024);
            ushort4 o;
            o.x = f2bf(v.x); o.y = f2bf(v.y); o.z = f2bf(v.z); o.w = f2bf(v.w);
            *(ushort4*)(dst + base + i * 1024) = o;
        }
        return;
    }
    __shared__ float t[64][65];
    const float* src; unsigned short* dst; int R, C, r0, c0;
    if (bid < 768) {
        const int which = bid >> 8, rem = bid & 255;
        const int rblk = rem & 15, zz = rem >> 4;
        src = (which == 0) ? W_Q : (which == 1) ? W_K : W_V;
        dst = (which == 0) ? WTq : (which == 1) ? WTkv : (WTkv + (1u << 20));
        src += (size_t)65536 * zz;
        dst += (size_t)65536 * zz;
        R = 1024; C = 64; r0 = rblk * 64; c0 = 0;
    } else {
        const int rem = bid - 768;
        src = W_O; dst = WTo; R = 1024; C = 1024;
        r0 = (rem & 15) * 64; c0 = (rem >> 4) * 64;
    }
    const int lr = tid >> 6, lc = tid & 63;
#pragma unroll
    for (int i = 0; i < 16; ++i)
        t[lr + i * 4][lc] = src[(size_t)(r0 + lr + i * 4) * C + c0 + lc];
    __syncthreads();
    // vectorized transposed write: thread (u = tid&15, w0 = tid>>4) writes
    // ushort4 at dst[(c0+c)*R + r0 + 4u]  (8B stores, 128B/row segments)
    const int u = tid & 15, w0 = tid >> 4;
#pragma unroll
    for (int i = 0; i < 4; ++i) {
        const int cl = w0 + i * 16;
        ushort4 o;
        o.x = f2bf(t[4 * u + 0][cl]);
        o.y = f2bf(t[4 * u + 1][cl]);
        o.z = f2bf(t[4 * u + 2][cl]);
        o.w = f2bf(t[4 * u + 3][cl]);
        *(ushort4*)&dst[(size_t)(c0 + cl) * R + r0 + 4 * u] = o;
    }
}

// C[4096 x N] = A[4096 x 1024] * W(+bias).  A bf16 [m][k]; WT bf16 [c][k].
// TM x 128 tile, BK=64, NT threads (NT/64 waves as (NW/2)x2; wave tile
// (2*TM/NW) x 64). global_load_lds staging with XOR slot-swizzle (source
// pre-swizzle + same involution on ds_read; 0 bank conflicts).
// COUNTED-VMCNT DOUBLE BUFFER (round 16, T3/T4 proper form): per K-step
// issue next tile's LOADS gll16 into buf^1, then s_waitcnt vmcnt(LOADS)
// (own current-tile loads landed; next's stay IN FLIGHT), then raw
// s_barrier (every wave waited before it => all staging visible), compute,
// second raw barrier (readers done before buf reuse). Never drains to 0 in
// the steady state -- unlike round 4's failed drain-at-barrier dbuf, and at
// TM=64/NT=512 the dbuf LDS (48KB) keeps 3 blocks/CU = 24 waves/CU, the
// measured-best TLP (rounds 12/14). sched_barrier(0) fences the asm waits.
// MODE 0: Q  -> per-head LN, bf16 out (Cb)
// MODE 1: KV -> N=2048; c<1024: K (LN, f32 Cf + bf16 Cb); c>=1024: V
//               (f32 Cf2 row-major + bf16 CbT transposed [b][h][d][s])
// MODE 2: O  -> f32 out (Cf)
template <int TM, int MODE, int NT>
__device__ __forceinline__ void gemm_body(
    unsigned short* __restrict__ As,   // [2][TM][64]
    unsigned short* __restrict__ Bs,   // [2][128][64]
    int bx, int by, const unsigned short* __restrict__ Abf,
    const unsigned short* __restrict__ WT,
    const float* __restrict__ biasK, const float* __restrict__ biasV,
    const float* __restrict__ lnw, const float* __restrict__ lnb,
    float* __restrict__ Cf, float* __restrict__ Cf2,
    unsigned short* __restrict__ Cb, unsigned short* __restrict__ CbT, int tid)
{
    constexpr int NW    = NT / 64;            // waves per block
    constexpr int WROWS = 2 * TM / NW;        // wave row-tile
    constexpr int MI    = WROWS / 16;         // acc row-fragments per wave
    constexpr int RP    = NT / 8;             // rows staged per gll16 pass
    constexpr int APASS = TM / RP;            // A staging passes (>=1)
    constexpr int BPASS = 128 / RP;           // B staging passes
    constexpr int LOADS = APASS + BPASS;      // gll16 per thread per stage

    const int m0 = by * TM;
    const int c0 = bx * 128;

    const int wid = tid >> 6, lane = tid & 63;
    const int wm = (wid >> 1) * WROWS;
    const int wn = (wid & 1) * 64;
    const int l15 = lane & 15, qd = lane >> 4;

    // staging: thread t -> physical LDS (row = t>>3 (+RP*j), slot = t&7).
    // Source col is pre-swizzled: s = p ^ (row&7). (RP multiple of 8.)
    const int srow  = tid >> 3;
    const int pslot = tid & 7;
    const int sslot = pslot ^ (srow & 7);
    const unsigned short* Ag = Abf + (size_t)(m0 + srow) * 1024 + sslot * 8;
    const unsigned short* Bg = WT  + (size_t)(c0 + srow) * 1024 + sslot * 8;
    unsigned short* Al = As + srow * 64 + pslot * 8;
    unsigned short* Bl = Bs + srow * 64 + pslot * 8;

    const f32x4 zero4 = {0.f, 0.f, 0.f, 0.f};
    f32x4 acc[MI][4];
#pragma unroll
    for (int mi = 0; mi < MI; ++mi)
#pragma unroll
        for (int ni = 0; ni < 4; ++ni) acc[mi][ni] = zero4;

    const int r7 = l15 & 7;   // row&7 of every fragment row this lane reads

#define STAGE(kb_, bi_)                                                        \
    {                                                                          \
        const size_t kof_ = (size_t)(kb_) * 64;                                \
        _Pragma("unroll")                                                      \
        for (int j = 0; j < APASS; ++j)                                        \
            gll16(Ag + (size_t)j * RP * 1024 + kof_,                           \
                  Al + (bi_) * (TM * 64) + j * RP * 64);                       \
        _Pragma("unroll")                                                      \
        for (int j = 0; j < BPASS; ++j)                                        \
            gll16(Bg + (size_t)j * RP * 1024 + kof_,                           \
                  Bl + (bi_) * (128 * 64) + j * RP * 64);                      \
    }

    STAGE(0, 0)
    for (int kb = 0; kb < 16; ++kb) {
        const int cur = kb & 1;
        if (kb < 15) {
            STAGE(kb + 1, cur ^ 1)          // next tile's loads stay in flight
            waitv<LOADS>();                 // own current-tile loads landed
        } else {
            waitv<0>();
        }
        __builtin_amdgcn_sched_barrier(0);
        __builtin_amdgcn_s_barrier();       // all waves' staging visible
        __builtin_amdgcn_sched_barrier(0);
#pragma unroll
        for (int ks = 0; ks < 2; ++ks) {
            const int cs = ((ks * 4 + qd) ^ r7) * 8;   // swizzled col (shorts)
            bf16x8 af[MI], bfr[4];
#pragma unroll
            for (int mi = 0; mi < MI; ++mi)
                af[mi] = *(const bf16x8*)(As + cur * (TM * 64) +
                                          (wm + mi * 16 + l15) * 64 + cs);
#pragma unroll
            for (int ni = 0; ni < 4; ++ni)
                bfr[ni] = *(const bf16x8*)(Bs + cur * (128 * 64) +
                                           (wn + ni * 16 + l15) * 64 + cs);
#pragma unroll
            for (int mi = 0; mi < MI; ++mi)
#pragma unroll
                for (int ni = 0; ni < 4; ++ni)
                    acc[mi][ni] = __builtin_amdgcn_mfma_f32_16x16x32_bf16(
                        af[mi], bfr[ni], acc[mi][ni], 0, 0, 0);
        }
        __builtin_amdgcn_sched_barrier(0);
        __builtin_amdgcn_s_barrier();       // readers done before buf reuse
    }
#undef STAGE

    const float* bias = (MODE == 1 && c0 >= 1024) ? biasV : biasK;
    float bv[4];
#pragma unroll
    for (int ni = 0; ni < 4; ++ni) bv[ni] = bias[(c0 + wn + ni * 16 + l15) & 1023];
#pragma unroll
    for (int mi = 0; mi < MI; ++mi)
#pragma unroll
        for (int ni = 0; ni < 4; ++ni)
#pragma unroll
            for (int r = 0; r < 4; ++r) acc[mi][ni][r] += bv[ni];

    if constexpr (MODE != 2) {
        const bool doLN = (MODE == 0) || (c0 < 1024);
        if (doLN) {   // per-head LN: wave's 64 cols = exactly one head
            float w4[4], lb4[4];
#pragma unroll
            for (int ni = 0; ni < 4; ++ni) {
                w4[ni]  = lnw[ni * 16 + l15];
                lb4[ni] = lnb[ni * 16 + l15];
            }
#pragma unroll
            for (int mi = 0; mi < MI; ++mi)
#pragma unroll
                for (int r = 0; r < 4; ++r) {
                    float s1 = acc[mi][0][r] + acc[mi][1][r] + acc[mi][2][r] + acc[mi][3][r];
                    const float mu = gsum16(s1) * (1.0f / 64.0f);
                    float s2 = acc[mi][0][r] * acc[mi][0][r] + acc[mi][1][r] * acc[mi][1][r]
                             + acc[mi][2][r] * acc[mi][2][r] + acc[mi][3][r] * acc[mi][3][r];
                    const float var = gsum16(s2) * (1.0f / 64.0f) - mu * mu;
                    const float rstd = rsqrtf(var + 1e-5f);
#pragma unroll
                    for (int ni = 0; ni < 4; ++ni)
                        acc[mi][ni][r] = (acc[mi][ni][r] - mu) * rstd * w4[ni] + lb4[ni];
                }
        }
    }

    if constexpr (MODE == 0) {
#pragma unroll
        for (int mi = 0; mi < MI; ++mi)
#pragma unroll
            for (int r = 0; r < 4; ++r) {
                const size_t grow = m0 + wm + mi * 16 + qd * 4 + r;
#pragma unroll
                for (int ni = 0; ni < 4; ++ni)
                    Cb[grow * 1024 + c0 + wn + ni * 16 + l15] = f2bf(acc[mi][ni][r]);
            }
    } else if constexpr (MODE == 2) {
#pragma unroll
        for (int mi = 0; mi < MI; ++mi)
#pragma unroll
            for (int r = 0; r < 4; ++r) {
                const size_t grow = m0 + wm + mi * 16 + qd * 4 + r;
#pragma unroll
                for (int ni = 0; ni < 4; ++ni)
                    Cf[grow * 1024 + c0 + wn + ni * 16 + l15] = acc[mi][ni][r];
            }
    } else {
        if (c0 < 1024) {   // K half
#pragma unroll
            for (int mi = 0; mi < MI; ++mi)
#pragma unroll
                for (int r = 0; r < 4; ++r) {
                    const size_t grow = m0 + wm + mi * 16 + qd * 4 + r;
#pragma unroll
                    for (int ni = 0; ni < 4; ++ni) {
                        const int gcol = c0 + wn + ni * 16 + l15;
                        Cf[grow * 1024 + gcol] = acc[mi][ni][r];
                        Cb[grow * 1024 + gcol] = f2bf(acc[mi][ni][r]);
                    }
                }
        } else {           // V half: row-major f32 + transposed bf16
#pragma unroll
            for (int mi = 0; mi < MI; ++mi) {
                const int growb = m0 + wm + mi * 16 + qd * 4;
                const int bb_ = growb >> 11, ss = growb & 2047;
#pragma unroll
                for (int ni = 0; ni < 4; ++ni) {
                    const int gv = c0 - 1024 + wn + ni * 16 + l15;
                    const int hh = gv >> 6, dd = gv & 63;
#pragma unroll
                    for (int r = 0; r < 4; ++r)
                        Cf2[(size_t)(growb + r) * 1024 + gv] = acc[mi][ni][r];
                    ushort4 w;
                    w.x = f2bf(acc[mi][ni][0]); w.y = f2bf(acc[mi][ni][1]);
                    w.z = f2bf(acc[mi][ni][2]); w.w = f2bf(acc[mi][ni][3]);
                    *(ushort4*)&CbT[(((size_t)bb_ * NH_ + hh) * DH_ + dd) * SQ_ + ss] = w;
                }
            }
        }
    }
}

// KV gemm (1024 blocks) + Q gemm (512 blocks) in one 1536-block launch.
// TM=64/NT=512 double-buffered: 48KB LDS -> 3 blocks/CU = 24 waves/CU
// (the measured-best TLP) with the counted-vmcnt pipeline.
__global__ __launch_bounds__(512) void qkv_fused(
    const unsigned short* __restrict__ xqbf, const unsigned short* __restrict__ xkvbf,
    const unsigned short* __restrict__ WTq, const unsigned short* __restrict__ WTkv,
    const float* __restrict__ b_Q, const float* __restrict__ b_K,
    const float* __restrict__ b_V,
    const float* __restrict__ ln1w, const float* __restrict__ ln1b,
    const float* __restrict__ ln2w, const float* __restrict__ ln2b,
    float* __restrict__ kout, float* __restrict__ vout,
    unsigned short* __restrict__ qz, unsigned short* __restrict__ kbf,
    unsigned short* __restrict__ vbfT)
{
    __shared__ __align__(16) unsigned short As[2 * 64 * 64];
    __shared__ __align__(16) unsigned short Bs[2 * 128 * 64];
    const int bid = blockIdx.x, tid = threadIdx.x;
    if (bid < 1024) {
        gemm_body<64, 1, 512>(As, Bs, bid & 15, bid >> 4, xkvbf, WTkv, b_K, b_V,
                              ln2w, ln2b, kout, vout, kbf, vbfT, tid);
    } else {
        const int b2 = bid - 1024;
        gemm_body<64, 0, 512>(As, Bs, b2 & 7, b2 >> 3, xqbf, WTq, b_Q, nullptr,
                              ln1w, ln1b, nullptr, nullptr, qz, nullptr, tid);
    }
}

// TM=64/NT=512 pipelined, grid 8x64 = 512 blocks = 2/CU = 16 waves/CU.
__global__ __launch_bounds__(512) void o_gemm(
    const unsigned short* __restrict__ zbf, const unsigned short* __restrict__ WTo,
    const float* __restrict__ b_O, float* __restrict__ out)
{
    __shared__ __align__(16) unsigned short As[2 * 64 * 64];
    __shared__ __align__(16) unsigned short Bs[2 * 128 * 64];
    gemm_body<64, 2, 512>(As, Bs, blockIdx.x, blockIdx.y, zbf, WTo, b_O, nullptr,
                          nullptr, nullptr, out, nullptr, nullptr, nullptr,
                          threadIdx.x);
}

// causal flash attention, S^T formulation; 64 q-rows/block; PAIRED hi-lo
// q-tiles (uniform 34 kv-tiles/block -- robust to undefined dispatch order,
// which broke the unpaired variants in rounds 1/8).
// 8-WAVE KV-PARITY SPLIT: block = 512 threads. Wave (g = wid&3, p = wid>>2):
// group g owns q-rows g*16+l15; parity p owns kv-tiles == p (mod 2).
// STATIC-MAX softmax (no running max) makes kv-splitting embarrassingly
// parallel: partials combine as z = z0+z1, l = l0+l1 via one LDS exchange
// per pass. 2 blocks x 8 waves = 16 waves/CU.
// SUPER-TILE DOUBLE BUFFER: one barrier per super-step: prefetch regs at
// top, compute buf[cur], late-write buf[cur^1], single barrier.
// REGISTER PV (round 11): pa=bf16(s) feeds v_mfma 16x16x16 directly; V read
// from VsT as bf16x4 (2-way bank aliasing = free). Epilogue combine reuses
// staging LDS as scratch after a barrier.
__global__ __launch_bounds__(512) void attn_mfma(
    unsigned short* __restrict__ qz, const unsigned short* __restrict__ kbf,
    const unsigned short* __restrict__ vbfT)
{
    __shared__ __align__(16) unsigned short Ks[2][128][72];    // [buf][kv][d]
    __shared__ __align__(16) unsigned short VsT[2][64][136];   // [buf][d][kv]

    const int tid = threadIdx.x;
    const int h = blockIdx.y, b = blockIdx.z;
    const int wid = tid >> 6, lane = tid & 63;
    const int g = wid & 3, p = wid >> 2;      // q-group, kv-parity
    const int l15 = lane & 15, qd = lane >> 4;
    const int srow = tid >> 2, scol = (tid & 3) * 16;   // K staging (128 rows)
    const int vrow = tid >> 3, vcol = (tid & 7) * 16;   // V staging (64 rows)

    const size_t kbase = (size_t)b * SQ_ * DM_ + (size_t)h * DH_;
    const size_t vbase = ((size_t)b * NH_ + h) * DH_ * (size_t)SQ_;
    const f32x4 zero4 = {0.f, 0.f, 0.f, 0.f};
    const float LOG2E = 1.44269504f, MBIAS = 46.1662413f;   // 32*log2(e)

    float* zs = (float*)&Ks[0][0][0];    // epilogue scratch (aliases Ks[0], 16KB)
    float* ls = (float*)&VsT[0][0][0];   // epilogue scratch (aliases VsT[0], 1KB)

    for (int pass = 0; pass < 2; ++pass) {
        const int qt = pass ? blockIdx.x : 31 - blockIdx.x;   // bx 0..15

        // Q fragments (B-operand: n=l15 -> qrow, k=qd*8+j -> d), direct global
        bf16x8 qf[2];
        {
            const unsigned short* qp =
                qz + kbase + (size_t)(qt * 64 + g * 16 + l15) * DM_ + qd * 8;
            qf[0] = *(const bf16x8*)(qp);
            qf[1] = *(const bf16x8*)(qp + 32);
        }

        f32x4 z[4];
#pragma unroll
        for (int ni = 0; ni < 4; ++ni) z[ni] = zero4;
        float l_i = 0.f;

        {   // stage super-tile 0 into buf0 (prior pass's last barrier protects)
            const unsigned short* ks = kbf + kbase + (size_t)srow * DM_ + scol;
            const u16x8 a0 = *(const u16x8*)(ks);
            const u16x8 a1 = *(const u16x8*)(ks + 8);
            const unsigned short* vs = vbfT + vbase + (size_t)vrow * SQ_ + vcol;
            const u16x8 b0 = *(const u16x8*)(vs);
            const u16x8 b1 = *(const u16x8*)(vs + 8);
            *(u16x8*)&Ks[0][srow][scol + 0]  = a0;
            *(u16x8*)&Ks[0][srow][scol + 8]  = a1;
            *(u16x8*)&VsT[0][vrow][vcol + 0] = b0;
            *(u16x8*)&VsT[0][vrow][vcol + 8] = b1;
        }
        __syncthreads();

        const int NS = (qt >> 1) + 1;   // super-steps (2 kv-tiles each)
        for (int st = 0; st < NS; ++st) {
            const int cur = st & 1;

            // issue next super-tile's global loads (overlap with compute)
            u16x8 kr0, kr1, vr0, vr1;
            if (st < NS - 1) {
                const unsigned short* ks =
                    kbf + kbase + (size_t)((st + 1) * 128 + srow) * DM_ + scol;
                kr0 = *(const u16x8*)(ks);
                kr1 = *(const u16x8*)(ks + 8);
                const unsigned short* vs =
                    vbfT + vbase + (size_t)vrow * SQ_ + (st + 1) * 128 + vcol;
                vr0 = *(const u16x8*)(vs);
                vr1 = *(const u16x8*)(vs + 8);
            }

            const int kt = st * 2 + p;   // this wave's kv-tile
            if (kt <= qt) {
                // S^T = K Q^T : lane holds S^T[kv=mi*16+qd*4+r][q=l15]
                f32x4 s[4];
#pragma unroll
                for (int mi = 0; mi < 4; ++mi) s[mi] = zero4;
#pragma unroll
                for (int ks2 = 0; ks2 < 2; ++ks2)
#pragma unroll
                    for (int mi = 0; mi < 4; ++mi) {
                        const bf16x8 af = *(const bf16x8*)
                            &Ks[cur][p * 64 + mi * 16 + l15][ks2 * 32 + qd * 8];
                        s[mi] = __builtin_amdgcn_mfma_f32_16x16x32_bf16(
                            af, qf[ks2], s[mi], 0, 0, 0);
                    }

                if (kt == qt) {   // causal mask (tile-local): kv > q
#pragma unroll
                    for (int mi = 0; mi < 4; ++mi)
#pragma unroll
                        for (int r = 0; r < 4; ++r)
                            if (mi * 16 + qd * 4 + r > g * 16 + l15)
                                s[mi][r] = -3.0e38f;
                }

                // static-max softmax: p' = exp2(s*log2e - 32*log2e)
                float ts[4];
                bf16x4 pa[4];
#pragma unroll
                for (int mi = 0; mi < 4; ++mi) {
#pragma unroll
                    for (int r = 0; r < 4; ++r)
                        s[mi][r] = __builtin_amdgcn_exp2f(
                            fmaf(s[mi][r], LOG2E, -MBIAS));
                    ts[mi] = (s[mi][0] + s[mi][1]) + (s[mi][2] + s[mi][3]);
                    pa[mi][0] = (short)f2bf(s[mi][0]);
                    pa[mi][1] = (short)f2bf(s[mi][1]);
                    pa[mi][2] = (short)f2bf(s[mi][2]);
                    pa[mi][3] = (short)f2bf(s[mi][3]);
                }
                float rs = (ts[0] + ts[1]) + (ts[2] + ts[3]);
                rs += __shfl_xor(rs, 16);
                rs += __shfl_xor(rs, 32);
                l_i += rs;

                // z += P V, P direct from registers (16x16x16)
#pragma unroll
                for (int mi = 0; mi < 4; ++mi)
#pragma unroll
                    for (int ni = 0; ni < 4; ++ni) {
                        const bf16x4 bv = *(const bf16x4*)
                            &VsT[cur][ni * 16 + l15][p * 64 + mi * 16 + qd * 4];
                        z[ni] = mfma16(pa[mi], bv, z[ni]);
                    }
            }

            // late write of the prefetched super-tile into the other buffer;
            // its last readers finished before the PREVIOUS barrier
            if (st < NS - 1) {
                *(u16x8*)&Ks[cur ^ 1][srow][scol + 0]  = kr0;
                *(u16x8*)&Ks[cur ^ 1][srow][scol + 8]  = kr1;
                *(u16x8*)&VsT[cur ^ 1][vrow][vcol + 0] = vr0;
                *(u16x8*)&VsT[cur ^ 1][vrow][vcol + 8] = vr1;
            }
            __syncthreads();   // single barrier per super-step
        }

        // combine kv-parity partials: z = z0 + z1, l = l0 + l1
        if (p == 1) {
#pragma unroll
            for (int ni = 0; ni < 4; ++ni)
                *(f32x4*)&zs[((g * 4 + ni) * 64 + lane) * 4] = z[ni];
            ls[g * 64 + lane] = l_i;
        }
        __syncthreads();
        if (p == 0) {
            const float l_tot = l_i + ls[g * 64 + lane];
#pragma unroll
            for (int ni = 0; ni < 4; ++ni) {
                const f32x4 zo = *(const f32x4*)&zs[((g * 4 + ni) * 64 + lane) * 4];
#pragma unroll
                for (int r = 0; r < 4; ++r) z[ni][r] += zo[r];
            }
            const float linv = 1.0f / l_tot;
#pragma unroll
            for (int r = 0; r < 4; ++r) {
                const float lr_ = __shfl(linv, qd * 4 + r);
                const size_t row = (size_t)qt * 64 + g * 16 + qd * 4 + r;
#pragma unroll
                for (int ni = 0; ni < 4; ++ni)
                    qz[kbase + row * DM_ + ni * 16 + l15] = f2bf(z[ni][r] * lr_);
            }
        }
        __syncthreads();   // scratch reads done before next pass restages
    }
}

extern "C" void kernel_launch(void* const* d_in, const int* in_sizes, int n_in,
                              void* d_out, int out_size, void* d_ws, size_t ws_size,
                              hipStream_t stream)
{
    const float* x_q  = (const float*)d_in[0];
    const float* x_kv = (const float*)d_in[1];
    // d_in[2] = mask (causal tril) -- computed analytically
    const float* W_Q  = (const float*)d_in[3];
    const float* W_K  = (const float*)d_in[4];
    const float* W_V  = (const float*)d_in[5];
    const float* W_O  = (const float*)d_in[6];
    const float* b_Q  = (const float*)d_in[7];
    const float* b_K  = (const float*)d_in[8];
    const float* b_V  = (const float*)d_in[9];
    const float* b_O  = (const float*)d_in[10];
    const float* ln1w = (const float*)d_in[11];
    const float* ln1b = (const float*)d_in[12];
    const float* ln2w = (const float*)d_in[13];
    const float* ln2b = (const float*)d_in[14];

    const size_t NTOK = (size_t)B_ * SQ_;          // 4096
    float* out  = (float*)d_out;
    float* kout = out + NTOK * DM_;
    float* vout = kout + NTOK * DM_;

    // bf16 copies of x_q/x_kv live in the `out` region (16 MB) of d_out:
    // written by prep_all, read by qkv_fused, overwritten by o_gemm last.
    unsigned short* xqbf  = (unsigned short*)out;
    unsigned short* xkvbf = xqbf + (1u << 22);

    unsigned short* wsu  = (unsigned short*)d_ws;
    unsigned short* WTq  = wsu;                        // 1M elems
    unsigned short* WTkv = WTq + (1u << 20);           // 2M (K^T | V^T)
    unsigned short* WTo  = WTkv + (2u << 20);          // 1M
    unsigned short* qz   = WTo + (1u << 20);           // 4M
    unsigned short* kbf  = qz + (1u << 22);            // 4M
    unsigned short* vbfT = kbf + (1u << 22);           // 4M -> 32 MiB total

    prep_all<<<2048, 256, 0, stream>>>(W_Q, W_K, W_V, W_O, x_q, x_kv,
                                       WTq, WTkv, WTo, xqbf, xkvbf);

    qkv_fused<<<1536, 512, 0, stream>>>(xqbf, xkvbf, WTq, WTkv, b_Q, b_K, b_V,
                                        ln1w, ln1b, ln2w, ln2b,
                                        kout, vout, qz, kbf, vbfT);

    attn_mfma<<<dim3(16, NH_, B_), 512, 0, stream>>>(qz, kbf, vbfT);

    o_gemm<<<dim3(8, 64), 512, 0, stream>>>(qz, WTo, b_O, out);
}